// Round 11
// baseline (249.303 us; speedup 1.0000x reference)
//
#include <hip/hip_runtime.h>
#include <stdint.h>

#define B_ 2048
#define T_ 256
#define V_ 128
#define E_ 128
#define H_ 64
#define G4_ 256  // 4*H
#define POS_W 20.0f
#define CH_ 544  // f16 per A-chunk in LDS: 512 + 32 pad (splits replica-write banks)

typedef _Float16 half1;
typedef __attribute__((ext_vector_type(8))) _Float16 f16x8;
typedef __attribute__((ext_vector_type(4))) float f32x4;

#if __has_builtin(__builtin_amdgcn_exp2f)
#define EXP2F(x) __builtin_amdgcn_exp2f(x)
#else
#define EXP2F(x) exp2f(x)
#endif

#if __has_builtin(__builtin_amdgcn_rcpf)
#define RCPF(x) __builtin_amdgcn_rcpf(x)
#else
#define RCPF(x) (1.0f / (x))
#endif

__device__ __forceinline__ float sigm(float x) {
    return RCPF(1.0f + EXP2F(-1.44269504f * x));
}
__device__ __forceinline__ float tanhr(float x) {
    // tanh(x) = 1 - 2/(e^(2x)+1); exp2 over/underflow saturates correctly
    float t = EXP2F(2.88539008f * x);
    return 1.0f - 2.0f * RCPF(t + 1.0f);
}

// ---------------------------------------------------------------------------
// k_prep: projC[v][u][g] = dot(emb[v], W_ih[g*64+u]) + b_ih + b_hh   (f32)
// Layout [v][unit][gate]: LSTM kernel gathers one float4 per (v,unit).
// Block 0 / tid 0 zeroes the loss accumulator.
// ---------------------------------------------------------------------------
__global__ void k_prep(const float* __restrict__ emb, const float* __restrict__ Wih,
                       const float* __restrict__ bih, const float* __restrict__ bhh,
                       float* __restrict__ projC, float* __restrict__ loss_slot) {
    int tid = threadIdx.x;  // 0..255; u = tid>>2, g = tid&3
    int v = blockIdx.x;
    if (v == 0 && tid == 0) *loss_slot = 0.0f;
    int u = tid >> 2, g = tid & 3;
    int row = g * 64 + u;
    const float4* e4 = (const float4*)(emb + v * E_);
    const float4* w4 = (const float4*)(Wih + row * E_);
    float acc = bih[row] + bhh[row];
#pragma unroll
    for (int i = 0; i < E_ / 4; ++i) {
        float4 a = e4[i];
        float4 b = w4[i];
        acc += a.x * b.x + a.y * b.y + a.z * b.z + a.w * b.w;
    }
    projC[v * G4_ + tid] = acc;  // coalesced
}

// ---------------------------------------------------------------------------
// k_lstm: barrier-free MFMA recurrence. ONE batch row per WAVE; 4 independent
// waves per block; 512 blocks (2048 waves = 2/SIMD). h-exchange is intra-wave
// (wave-private LDS + lgkmcnt lockstep) -- NO s_barrier in the T-loop, so
// co-resident waves free-run and hide each other's latency (R8/R9: the block
// barrier pinned step at 944 cyc regardless of occupancy or de-phasing).
//   A-rows {0,4,8,12} = the row's h replicated (other rows garbage: D[m]
//   depends only on A[m]); tile tau=4g+uq covers gate g, units 16uq..+15, so
//   lane l=16q+cc reads all 4 gates of unit l from reg[0] of the uq==q tiles
//   via 3 cndmasks/gate. 32 MFMA/wave-step; the 128-VGPR B-frag array may
//   live in AGPRs -- free for MFMA operands.
// R10 NaN bug: zero-init covered only chunk 0 (272 of 544 dwords); chunk 1
// garbage (k=32..63) poisoned step-0 MFMA. Fixed: zero all 544 dwords.
// ---------------------------------------------------------------------------
__launch_bounds__(256, 2)
__global__ void k_lstm(const int* __restrict__ x, const float* __restrict__ Whh,
                       const float* __restrict__ projC, const float* __restrict__ Wfc,
                       const float* __restrict__ bfc, const float* __restrict__ targets,
                       float* __restrict__ logits, float* __restrict__ loss_slot) {
    int t = threadIdx.x;         // 0..255
    int w = t >> 6, l = t & 63;  // wave, lane
    int q = l >> 4, cc = l & 15;
    int row = blockIdx.x * 4 + w;  // this wave's batch row

    __shared__ __align__(16) half1 hf[4][2 * CH_];  // wave-private A buffers
    __shared__ __align__(16) int tok[4][T_];        // wave-private tokens
    __shared__ float zred[4];

    // stage tokens (16B/lane, coalesced) into this wave's buffer
    {
        int4 tk = *(const int4*)(x + row * T_ + 4 * l);
        *(int4*)&tok[w][4 * l] = tk;
    }
    // zero own A buffer: 2*CH_ = 1088 f16 = 544 dwords (8*64 + 32).
    {
        uint32_t* hz = (uint32_t*)hf[w];
#pragma unroll
        for (int i = 0; i < 8; ++i) hz[l + 64 * i] = 0u;  // dwords 0..511
        if (l < 32) hz[512 + l] = 0u;                     // dwords 512..543
    }

    // B-fragments from W_hh (f32, L2): tile tau = 4g+uq, K-chunk c.
    // frag elem j: B[k=c*32+q*8+j][col cc] = Whh[g*64+16uq+cc][k]
    f16x8 bf[16][2];
#pragma unroll
    for (int g = 0; g < 4; ++g) {
#pragma unroll
        for (int uq = 0; uq < 4; ++uq) {
            int r = g * 64 + 16 * uq + cc;
#pragma unroll
            for (int c = 0; c < 2; ++c) {
                int kb = c * 32 + q * 8;
                float4 w0 = *(const float4*)(Whh + r * H_ + kb);
                float4 w1 = *(const float4*)(Whh + r * H_ + kb + 4);
                f16x8 tmp;
                tmp[0] = (half1)w0.x; tmp[1] = (half1)w0.y;
                tmp[2] = (half1)w0.z; tmp[3] = (half1)w0.w;
                tmp[4] = (half1)w1.x; tmp[5] = (half1)w1.y;
                tmp[6] = (half1)w1.z; tmp[7] = (half1)w1.w;
                bf[g * 4 + uq][c] = tmp;
            }
        }
    }

    // h-write base for unit l: A[m][k=l] lives (chunk l>>5) at f16 index
    // chunk*CH_ + ((l&31)>>3)*128 + m*8 + (l&7); replicas m in {0,4,8,12}
    // -> +0,+32,+64,+96.
    int wbase = (l >> 5) * CH_ + ((l & 31) >> 3) * 128 + (l & 7);

    float cS = 0.0f, hS = 0.0f;

    // proj prefetch depth 2 (no barrier ever drains vmcnt)
    f32x4 pp = *(const f32x4*)(projC + tok[w][0] * G4_ + 4 * l);
    f32x4 pn = *(const f32x4*)(projC + tok[w][1] * G4_ + 4 * l);

    for (int step = 0; step < T_; ++step) {
        // depth-2 prefetch (consumed at step+2; wraps harmlessly)
        int tk2 = tok[w][(step + 2) & (T_ - 1)];
        f32x4 p2 = *(const f32x4*)(projC + tk2 * G4_ + 4 * l);

        // A-fragments of h_t (lane-contiguous b128, conflict-free)
        f16x8 a0 = *(const f16x8*)&hf[w][l * 8];
        f16x8 a1 = *(const f16x8*)&hf[w][CH_ + l * 8];

        f32x4 z4 = {0.0f, 0.0f, 0.0f, 0.0f};
        float gv[4];
#pragma unroll
        for (int g = 0; g < 4; ++g) {
            f32x4 dA = __builtin_amdgcn_mfma_f32_16x16x32_f16(a0, bf[g * 4 + 0][0], z4, 0, 0, 0);
            dA = __builtin_amdgcn_mfma_f32_16x16x32_f16(a1, bf[g * 4 + 0][1], dA, 0, 0, 0);
            f32x4 dB = __builtin_amdgcn_mfma_f32_16x16x32_f16(a0, bf[g * 4 + 1][0], z4, 0, 0, 0);
            dB = __builtin_amdgcn_mfma_f32_16x16x32_f16(a1, bf[g * 4 + 1][1], dB, 0, 0, 0);
            f32x4 dC = __builtin_amdgcn_mfma_f32_16x16x32_f16(a0, bf[g * 4 + 2][0], z4, 0, 0, 0);
            dC = __builtin_amdgcn_mfma_f32_16x16x32_f16(a1, bf[g * 4 + 2][1], dC, 0, 0, 0);
            f32x4 dD = __builtin_amdgcn_mfma_f32_16x16x32_f16(a0, bf[g * 4 + 3][0], z4, 0, 0, 0);
            dD = __builtin_amdgcn_mfma_f32_16x16x32_f16(a1, bf[g * 4 + 3][1], dD, 0, 0, 0);
            // lane group q keeps tile uq==q (reg0 = replicated row 4q)
            float lo = (q == 0) ? dA[0] : dB[0];
            float hi = (q == 2) ? dC[0] : dD[0];
            gv[g] = (q < 2) ? lo : hi;
        }

        // cell update for (row, unit l); pp loaded 2 steps ago
        float i_ = sigm(gv[0] + pp.x);
        float f_ = sigm(gv[1] + pp.y);
        float g_ = tanhr(gv[2] + pp.z);
        float o_ = sigm(gv[3] + pp.w);
        cS = f_ * cS + i_ * g_;
        hS = o_ * tanhr(cS);

        // publish h_{t+1}: 4 replica b16 writes (A-rows 0,4,8,12); intra-wave
        // lockstep + lgkmcnt gives write->read ordering, no barrier
        half1 hv = (half1)hS;
        hf[w][wbase] = hv;
        hf[w][wbase + 32] = hv;
        hf[w][wbase + 64] = hv;
        hf[w][wbase + 96] = hv;

        pp = pn;
        pn = p2;
    }

    // epilogue: per-wave logits + loss term; one atomic per block
    float part = hS * Wfc[l];
#pragma unroll
    for (int off = 32; off > 0; off >>= 1) part += __shfl_down(part, off, 64);
    if (l == 0) {
        float z = part + bfc[0];
        logits[row] = z;
        float tg = targets[row];
        float e = EXP2F(-1.44269504f * fabsf(z));
        float lsp = fminf(z, 0.0f) - log1pf(e);
        float lsn = lsp - z;
        zred[w] = -(POS_W * tg * lsp + (1.0f - tg) * lsn) * (1.0f / (float)B_);
    }
    __syncthreads();
    if (t == 0) atomicAdd(loss_slot, zred[0] + zred[1] + zred[2] + zred[3]);
}

// ---------------------------------------------------------------------------
extern "C" void kernel_launch(void* const* d_in, const int* in_sizes, int n_in,
                              void* d_out, int out_size, void* d_ws, size_t ws_size,
                              hipStream_t stream) {
    const int* x = (const int*)d_in[0];
    const float* targets = (const float*)d_in[1];
    const float* emb = (const float*)d_in[2];
    const float* Wih = (const float*)d_in[3];
    const float* Whh = (const float*)d_in[4];
    const float* bih = (const float*)d_in[5];
    const float* bhh = (const float*)d_in[6];
    const float* Wfc = (const float*)d_in[7];
    const float* bfc = (const float*)d_in[8];
    float* out = (float*)d_out;  // [0..2047] logits, [2048] loss

    float* projC = (float*)d_ws;  // 128*256*4 = 128 KiB

    k_prep<<<dim3(V_), dim3(256), 0, stream>>>(emb, Wih, bih, bhh, projC, out + B_);
    k_lstm<<<dim3(B_ / 4), dim3(256), 0, stream>>>(x, Whh, projC, Wfc, bfc, targets, out,
                                                   out + B_);
}

// Round 12
// 196.865 us; speedup vs baseline: 1.2664x; 1.2664x over previous
//
#include <hip/hip_runtime.h>
#include <stdint.h>

#define B_ 2048
#define T_ 256
#define V_ 128
#define E_ 128
#define H_ 64
#define G4_ 256  // 4*H
#define POS_W 20.0f

typedef _Float16 half1;
typedef __attribute__((ext_vector_type(8))) _Float16 f16x8;
typedef __attribute__((ext_vector_type(4))) float f32x4;

#if __has_builtin(__builtin_amdgcn_exp2f)
#define EXP2F(x) __builtin_amdgcn_exp2f(x)
#else
#define EXP2F(x) exp2f(x)
#endif

#if __has_builtin(__builtin_amdgcn_rcpf)
#define RCPF(x) __builtin_amdgcn_rcpf(x)
#else
#define RCPF(x) (1.0f / (x))
#endif

__device__ __forceinline__ float sigm(float x) {
    return RCPF(1.0f + EXP2F(-1.44269504f * x));
}
__device__ __forceinline__ float tanhr(float x) {
    // tanh(x) = 1 - 2/(e^(2x)+1); exp2 over/underflow saturates correctly
    float t = EXP2F(2.88539008f * x);
    return 1.0f - 2.0f * RCPF(t + 1.0f);
}

// lgkmcnt-only barrier: keeps L2 proj prefetches (vmcnt) in flight across the
// interval boundary (R7: removing the vmcnt drain cut 1422->1000 cyc/step).
__device__ __forceinline__ void lds_barrier() {
    asm volatile("s_waitcnt lgkmcnt(0)\n\ts_barrier" ::: "memory");
}

// ---------------------------------------------------------------------------
// k_prep: projC[v][u][g] = dot(emb[v], W_ih[g*64+u]) + b_ih + b_hh   (f32)
// Layout [v][unit][gate]: LSTM kernel gathers one float4 per (v,unit).
// ---------------------------------------------------------------------------
__global__ void k_prep(const float* __restrict__ emb, const float* __restrict__ Wih,
                       const float* __restrict__ bih, const float* __restrict__ bhh,
                       float* __restrict__ projC, float* __restrict__ loss_slot) {
    int tid = threadIdx.x;  // 0..255; u = tid>>2, g = tid&3
    int v = blockIdx.x;
    if (v == 0 && tid == 0) *loss_slot = 0.0f;
    int u = tid >> 2, g = tid & 3;
    int row = g * 64 + u;
    const float4* e4 = (const float4*)(emb + v * E_);
    const float4* w4 = (const float4*)(Wih + row * E_);
    float acc = bih[row] + bhh[row];
#pragma unroll
    for (int i = 0; i < E_ / 4; ++i) {
        float4 a = e4[i];
        float4 b = w4[i];
        acc += a.x * b.x + a.y * b.y + a.z * b.z + a.w * b.w;
    }
    projC[v * G4_ + tid] = acc;  // coalesced
}

// ---------------------------------------------------------------------------
// k_lstm: anti-phase dual-group MFMA recurrence.
// Block = 512 thr = 8 waves = TWO independent R8-style 4-row groups:
//   X = waves 0-3 (rows b0..b0+3), Y = waves 4-7 (rows b0+4..b0+7).
// Round-robin wave placement puts 1 X-wave + 1 Y-wave on each SIMD. One
// barrier per HALF-step: while X runs its MFMA phase, Y runs its nonlin
// phase, then swap. The co-scheduled waves execute different pipe classes
// by construction, so the R8/R9 barrier convoy (homogeneous waves phase-
// locking, step = VALU-sum + MFMA + idle = 944 cyc) becomes the desired
// interleave: interval ~ max(VALU ~230, MFMA ~155).
// Within a group everything is R8's verified mapping: lane (q,cc) of wave wl
// owns cell (row q, unit u=16wl+cc); gates travel MFMA->nonlin in REGISTERS
// (gA stash, same wave does both phases); h via double-buffered A-layout LDS.
// ---------------------------------------------------------------------------
__launch_bounds__(512, 1)
__global__ void k_lstm(const int* __restrict__ x, const float* __restrict__ Whh,
                       const float* __restrict__ projC, const float* __restrict__ Wfc,
                       const float* __restrict__ bfc, const float* __restrict__ targets,
                       float* __restrict__ logits, float* __restrict__ loss_slot) {
    int b0 = blockIdx.x * 8;
    int t = threadIdx.x;               // 0..511
    int w8 = t >> 6, l = t & 63;       // wave 0..7, lane
    int grp = t >> 8;                  // 0 = X, 1 = Y
    int wl = w8 & 3;                   // wave within group (N-slice)
    int tg = t & 255;                  // thread within group
    int q = l >> 4, cc = l & 15;
    int u = 16 * wl + cc;              // unit owned (all 4 gates), batch row q
    int bg = b0 + 4 * grp;             // group's first batch row
    bool isY = (grp == 1);

    __shared__ __align__(16) half1 hf[2][2][1024];  // [grp][buf][A-layout h]
    __shared__ int xT[2][T_][4];                    // [grp][t][row]
    __shared__ float hfin[2][4][68];
    __shared__ float zred[8];

    // stage tokens (coalesced: fixed i, consecutive tg)
#pragma unroll
    for (int i = 0; i < 4; ++i) xT[grp][tg][i] = x[(bg + i) * T_ + tg];
    // zero both groups' h buffers: 2048 dwords / 512 threads
    ((float*)hf)[t] = 0.0f;
    ((float*)hf)[t + 512] = 0.0f;
    ((float*)hf)[t + 1024] = 0.0f;
    ((float*)hf)[t + 1536] = 0.0f;
    __syncthreads();

    // B-fragments from W_hh (f32, L2): N-tile jj (=gate), K-chunk c.
    // frag elem j: B[k=c*32+q*8+j][col cc] = Whh[jj*64+16wl+cc][k] (R5-R8 verified)
    f16x8 bf[4][2];
#pragma unroll
    for (int jj = 0; jj < 4; ++jj) {
#pragma unroll
        for (int c = 0; c < 2; ++c) {
            int row = jj * 64 + 16 * wl + cc;
            int kb = c * 32 + q * 8;
            float4 w0 = *(const float4*)(Whh + row * H_ + kb);
            float4 w1 = *(const float4*)(Whh + row * H_ + kb + 4);
            f16x8 tmp;
            tmp[0] = (half1)w0.x; tmp[1] = (half1)w0.y;
            tmp[2] = (half1)w0.z; tmp[3] = (half1)w0.w;
            tmp[4] = (half1)w1.x; tmp[5] = (half1)w1.y;
            tmp[6] = (half1)w1.z; tmp[7] = (half1)w1.w;
            bf[jj][c] = tmp;
        }
    }

    // h-write slot for (unit u, M-row 4q)  [R8-verified formula]
    int hbase = (u >> 5) * 512 + ((u >> 3) & 3) * 128 + (4 * q) * 8 + (u & 7);

    float cA = 0.0f, hA = 0.0f;
    float gA[4];  // gate stash, carried across the mid barrier in registers

    // proj prefetch depth 2
    f32x4 pp = *(const f32x4*)(projC + xT[grp][0][q] * G4_ + u * 4);
    f32x4 pn = *(const f32x4*)(projC + xT[grp][1][q] * G4_ + u * 4);
    int p = 0;

#define PHASE_MFMA()                                                                     \
    {                                                                                    \
        const f16x8 a0 = *(const f16x8*)&hf[grp][p][l * 8];                              \
        const f16x8 a1 = *(const f16x8*)&hf[grp][p][512 + l * 8];                        \
        f32x4 z4 = {0.0f, 0.0f, 0.0f, 0.0f};                                             \
        _Pragma("unroll") for (int jj = 0; jj < 4; ++jj) {                               \
            f32x4 d0 = __builtin_amdgcn_mfma_f32_16x16x32_f16(a0, bf[jj][0], z4, 0, 0, 0); \
            f32x4 d1 = __builtin_amdgcn_mfma_f32_16x16x32_f16(a1, bf[jj][1], z4, 0, 0, 0); \
            gA[jj] = d0[0] + d1[0];                                                      \
        }                                                                                \
    }

#define PHASE_NONLIN(tstep)                                                              \
    {                                                                                    \
        f32x4 p2 = *(const f32x4*)(projC + xT[grp][((tstep) + 2) & (T_ - 1)][q] * G4_ +  \
                                   u * 4);                                               \
        float i_ = sigm(gA[0] + pp.x);                                                   \
        float f_ = sigm(gA[1] + pp.y);                                                   \
        float g_ = tanhr(gA[2] + pp.z);                                                  \
        float o_ = sigm(gA[3] + pp.w);                                                   \
        cA = f_ * cA + i_ * g_;                                                          \
        hA = o_ * tanhr(cA);                                                             \
        hf[grp][p ^ 1][hbase] = (half1)hA;                                               \
        pp = pn;                                                                         \
        pn = p2;                                                                         \
        p ^= 1;                                                                          \
    }

    for (int step = 0; step < T_; ++step) {
        // interval 1: X -> MFMA(step), Y -> nonlin(step-1)
        if (!isY) {
            PHASE_MFMA();
        } else if (step > 0) {
            PHASE_NONLIN(step - 1);
        }
        lds_barrier();
        // interval 2: X -> nonlin(step), Y -> MFMA(step)
        if (!isY) {
            PHASE_NONLIN(step);
        } else {
            PHASE_MFMA();
        }
        lds_barrier();
    }
    if (isY) {
        PHASE_NONLIN(T_ - 1);
    }

    // epilogue: logits + fused loss (8 rows per block; wave w8 reduces one row)
    hfin[grp][q][u] = hA;
    __syncthreads();
    int rr = w8 & 3;
    int rowg = b0 + 4 * (w8 >> 2) + rr;
    float part = hfin[w8 >> 2][rr][l] * Wfc[l];
#pragma unroll
    for (int off = 32; off > 0; off >>= 1) part += __shfl_down(part, off, 64);
    if (l == 0) {
        float z = part + bfc[0];
        logits[rowg] = z;
        float tgt = targets[rowg];
        float e = EXP2F(-1.44269504f * fabsf(z));
        float lsp = fminf(z, 0.0f) - log1pf(e);
        float lsn = lsp - z;
        zred[w8] = -(POS_W * tgt * lsp + (1.0f - tgt) * lsn) * (1.0f / (float)B_);
    }
    __syncthreads();
    if (t == 0) {
        float s = 0.0f;
#pragma unroll
        for (int i = 0; i < 8; ++i) s += zred[i];
        atomicAdd(loss_slot, s);
    }
}

// ---------------------------------------------------------------------------
extern "C" void kernel_launch(void* const* d_in, const int* in_sizes, int n_in,
                              void* d_out, int out_size, void* d_ws, size_t ws_size,
                              hipStream_t stream) {
    const int* x = (const int*)d_in[0];
    const float* targets = (const float*)d_in[1];
    const float* emb = (const float*)d_in[2];
    const float* Wih = (const float*)d_in[3];
    const float* Whh = (const float*)d_in[4];
    const float* bih = (const float*)d_in[5];
    const float* bhh = (const float*)d_in[6];
    const float* Wfc = (const float*)d_in[7];
    const float* bfc = (const float*)d_in[8];
    float* out = (float*)d_out;  // [0..2047] logits, [2048] loss

    float* projC = (float*)d_ws;  // 128*256*4 = 128 KiB

    k_prep<<<dim3(V_), dim3(256), 0, stream>>>(emb, Wih, bih, bhh, projC, out + B_);
    k_lstm<<<dim3(B_ / 8), dim3(512), 0, stream>>>(x, Whh, projC, Wfc, bfc, targets, out,
                                                   out + B_);
}

// Round 13
// 164.067 us; speedup vs baseline: 1.5195x; 1.1999x over previous
//
#include <hip/hip_runtime.h>
#include <stdint.h>

#define B_ 2048
#define T_ 256
#define V_ 128
#define E_ 128
#define H_ 64
#define G4_ 256  // 4*H
#define POS_W 20.0f
#define MB_ 4            // batch rows per block: row j at M-row 4j (C-reg[0] of lane quad j)
#define NBLK_ (B_ / MB_) // 512 blocks = 2 blocks/CU = 2 waves/SIMD
typedef _Float16 half1;
typedef __attribute__((ext_vector_type(8))) _Float16 f16x8;
typedef __attribute__((ext_vector_type(4))) float f32x4;

#if __has_builtin(__builtin_amdgcn_exp2f)
#define EXP2F(x) __builtin_amdgcn_exp2f(x)
#else
#define EXP2F(x) exp2f(x)
#endif

#if __has_builtin(__builtin_amdgcn_rcpf)
#define RCPF(x) __builtin_amdgcn_rcpf(x)
#else
#define RCPF(x) (1.0f / (x))
#endif

__device__ __forceinline__ float sigm(float x) {
    return RCPF(1.0f + EXP2F(-1.44269504f * x));
}
__device__ __forceinline__ float tanhr(float x) {
    // tanh(x) = 1 - 2/(e^(2x)+1); exp2 over/underflow saturates correctly
    float t = EXP2F(2.88539008f * x);
    return 1.0f - 2.0f * RCPF(t + 1.0f);
}

// Barrier draining ONLY lgkmcnt: keeps L2 proj-prefetches (vmcnt) in flight
// across the step boundary (R6->R7: 1422 -> 1000 cyc/step). Safe: h-exchange
// is double-buffered; in-flight global loads only write registers.
__device__ __forceinline__ void lds_barrier() {
    asm volatile("s_waitcnt lgkmcnt(0)\n\ts_barrier" ::: "memory");
}

// ---------------------------------------------------------------------------
// k_prep: projC[v][u][g] = dot(emb[v], W_ih[g*64+u]) + b_ih + b_hh   (f32)
// Layout [v][unit][gate]: LSTM kernel gathers one float4 per (v,unit).
// Block 0 / tid 0 zeroes the loss accumulator.
// ---------------------------------------------------------------------------
__global__ void k_prep(const float* __restrict__ emb, const float* __restrict__ Wih,
                       const float* __restrict__ bih, const float* __restrict__ bhh,
                       float* __restrict__ projC, float* __restrict__ loss_slot) {
    int tid = threadIdx.x;  // 0..255; u = tid>>2, g = tid&3
    int v = blockIdx.x;
    if (v == 0 && tid == 0) *loss_slot = 0.0f;
    int u = tid >> 2, g = tid & 3;
    int row = g * 64 + u;
    const float4* e4 = (const float4*)(emb + v * E_);
    const float4* w4 = (const float4*)(Wih + row * E_);
    float acc = bih[row] + bhh[row];
#pragma unroll
    for (int i = 0; i < E_ / 4; ++i) {
        float4 a = e4[i];
        float4 b = w4[i];
        acc += a.x * b.x + a.y * b.y + a.z * b.z + a.w * b.w;
    }
    projC[v * G4_ + tid] = acc;  // coalesced
}

// ---------------------------------------------------------------------------
// k_lstm: MFMA recurrence, gate-permuted B, 1 cell per thread. (R8 structure,
// the empirical optimum of 12 structural probes: barrier-per-step floor
// ~950 cyc = issue(~470/SIMD) + chain/barrier(~470); barrier-free costs 4x
// MFMA (R11, saturated); anti-phase welding pays 2 barriers (R12).)
// Block = 4 batch rows (4 waves); 512 blocks -> 2 blocks/CU.
// Batch row j sits at M-row 4j: lane (q,cc) of wave w owns cell
// (row q, unit u=16w+cc) in C-reg[0] -- zero cross-lane traffic.
// h returns via double-buffered A-layout LDS; ONE lgkm-only barrier/step;
// projC prefetched from L2 at depth 2 (never waited on the step path).
// Micro-reorder vs R8: A-frag ds_reads issued at the chain head, prefetch
// addr-calc/issue moved after them (off the post-barrier critical path).
// ---------------------------------------------------------------------------
__launch_bounds__(256, 2)
__global__ void k_lstm(const int* __restrict__ x, const float* __restrict__ Whh,
                       const float* __restrict__ projC, const float* __restrict__ Wfc,
                       const float* __restrict__ bfc, const float* __restrict__ targets,
                       float* __restrict__ logits, float* __restrict__ loss_slot) {
    int b0 = blockIdx.x * MB_;
    int t = threadIdx.x;         // 0..255
    int w = t >> 6, l = t & 63;  // wave, lane
    int q = l >> 4, cc = l & 15;
    int u = 16 * w + cc;  // unit owned by this lane (all 4 gates), batch row q

    __shared__ __align__(16) half1 hf[2][1024];  // A-layout h, double-buffered
    __shared__ int xT[T_][MB_];                  // transposed token indices
    __shared__ float hfin[MB_][68];              // final h (padded)
    __shared__ float zred[MB_];

    // stage xT (coalesced: fixed i, consecutive t)
#pragma unroll
    for (int i = 0; i < MB_; ++i) xT[t][i] = x[(b0 + i) * T_ + t];
    ((float*)hf)[t] = 0.0f;
    ((float*)hf)[t + 256] = 0.0f;
    ((float*)hf)[t + 512] = 0.0f;
    ((float*)hf)[t + 768] = 0.0f;
    __syncthreads();

    // B-fragments inline from W_hh (f32, L2): N-tile jj (=gate), K-chunk c.
    // frag elem j: B[k=c*32+q*8+j][col cc] = Whh[jj*64+16w+cc][k]  (R5-R9 verified)
    f16x8 bf[4][2];
#pragma unroll
    for (int jj = 0; jj < 4; ++jj) {
#pragma unroll
        for (int c = 0; c < 2; ++c) {
            int row = jj * 64 + 16 * w + cc;
            int kb = c * 32 + q * 8;
            float4 w0 = *(const float4*)(Whh + row * H_ + kb);
            float4 w1 = *(const float4*)(Whh + row * H_ + kb + 4);
            f16x8 tmp;
            tmp[0] = (half1)w0.x; tmp[1] = (half1)w0.y;
            tmp[2] = (half1)w0.z; tmp[3] = (half1)w0.w;
            tmp[4] = (half1)w1.x; tmp[5] = (half1)w1.y;
            tmp[6] = (half1)w1.z; tmp[7] = (half1)w1.w;
            bf[jj][c] = tmp;
        }
    }

    // h-write slot for (unit u, M-row 4q):
    // f16 idx = (u>>5)*512 + ((u>>3)&3)*128 + (4q)*8 + (u&7)
    int hbase = (u >> 5) * 512 + ((u >> 3) & 3) * 128 + (4 * q) * 8 + (u & 7);

    float cA = 0.0f, hA = 0.0f;

    // prefetch proj for steps 0 and 1 (depth 2); same-q lanes broadcast-read xT
    f32x4 ppA = *(const f32x4*)(projC + xT[0][q] * G4_ + u * 4);
    f32x4 pnA = *(const f32x4*)(projC + xT[1][q] * G4_ + u * 4);

    int p = 0;
#pragma unroll 2
    for (int step = 0; step < T_; ++step) {
        // chain head: A-fragments of h_t first (conflict-free b128)
        const f16x8 a0 = *(const f16x8*)(hf[p] + l * 8);
        const f16x8 a1 = *(const f16x8*)(hf[p] + 512 + l * 8);

        // depth-2 prefetch issued off the chain head (consumed at step+2)
        f32x4 p2A = *(const f32x4*)(projC + xT[(step + 2) & (T_ - 1)][q] * G4_ + u * 4);

        // gates for (row q, unit u): only C-reg[0] is live
        f32x4 z4 = {0.0f, 0.0f, 0.0f, 0.0f};
        float gA[4];
#pragma unroll
        for (int jj = 0; jj < 4; ++jj) {
            f32x4 d0 = __builtin_amdgcn_mfma_f32_16x16x32_f16(a0, bf[jj][0], z4, 0, 0, 0);
            f32x4 d1 = __builtin_amdgcn_mfma_f32_16x16x32_f16(a1, bf[jj][1], z4, 0, 0, 0);
            gA[jj] = d0[0] + d1[0];
        }

        // cell update; pp was loaded 2 steps ago (never waited)
        float iA = sigm(gA[0] + ppA.x);
        float fA = sigm(gA[1] + ppA.y);
        float ggA = tanhr(gA[2] + ppA.z);
        float oA = sigm(gA[3] + ppA.w);
        cA = fA * cA + iA * ggA;
        hA = oA * tanhr(cA);

        // publish h_{t+1} (A-layout, other buffer)
        hf[p ^ 1][hbase] = (half1)hA;

        ppA = pnA;
        pnA = p2A;
        p ^= 1;
        lds_barrier();  // lgkmcnt-only: proj prefetches stay in flight
    }

    // epilogue: logits + fused loss
    hfin[q][u] = hA;
    __syncthreads();
    int m4 = t >> 6, uu = t & 63;  // wave m4 reduces batch row m4
    float part = hfin[m4][uu] * Wfc[uu];
#pragma unroll
    for (int off = 32; off > 0; off >>= 1) part += __shfl_down(part, off, 64);
    if (uu == 0) {
        float z = part + bfc[0];
        logits[b0 + m4] = z;
        float tg = targets[b0 + m4];
        float e = EXP2F(-1.44269504f * fabsf(z));
        float lsp = fminf(z, 0.0f) - log1pf(e);
        float lsn = lsp - z;
        zred[m4] = -(POS_W * tg * lsp + (1.0f - tg) * lsn) * (1.0f / (float)B_);
    }
    __syncthreads();
    if (t == 0) {
        float s = 0.0f;
#pragma unroll
        for (int i = 0; i < MB_; ++i) s += zred[i];
        atomicAdd(loss_slot, s);
    }
}

// ---------------------------------------------------------------------------
extern "C" void kernel_launch(void* const* d_in, const int* in_sizes, int n_in,
                              void* d_out, int out_size, void* d_ws, size_t ws_size,
                              hipStream_t stream) {
    const int* x = (const int*)d_in[0];
    const float* targets = (const float*)d_in[1];
    const float* emb = (const float*)d_in[2];
    const float* Wih = (const float*)d_in[3];
    const float* Whh = (const float*)d_in[4];
    const float* bih = (const float*)d_in[5];
    const float* bhh = (const float*)d_in[6];
    const float* Wfc = (const float*)d_in[7];
    const float* bfc = (const float*)d_in[8];
    float* out = (float*)d_out;  // [0..2047] logits, [2048] loss

    float* projC = (float*)d_ws;  // 128*256*4 = 128 KiB

    k_prep<<<dim3(V_), dim3(256), 0, stream>>>(emb, Wih, bih, bhh, projC, out + B_);
    k_lstm<<<dim3(NBLK_), dim3(256), 0, stream>>>(x, Whh, projC, Wfc, bfc, targets, out,
                                                  out + B_);
}